// Round 1
// baseline (341.545 us; speedup 1.0000x reference)
//
#include <hip/hip_runtime.h>
#include <hip/hip_bf16.h>

// out[b,e] = m[c,e] + sum_d z[b,d] * L[c,e,d],  c = components[b]
// fp32 in/out; bf16 MFMA internally.
// v2 structure: 3 kernels.
//  K1 build_map: bucket samples by component (counting sort), as before.
//  K2 zgather:   pre-gather + pre-convert Z to bf16 zb[k][slot][d] in workspace
//                (6.55 MB) -> kills the 32x fp32 Z re-read and all A converts.
//  K3 gmm_gemm:  registers-only GEMM, NO LDS, NO barriers. A frags load as one
//                16B bf16x8; B (L) frags as two f32x4 + in-reg convert. Depth-2
//                software pipeline (even/odd named register sets, no dynamic
//                indexing) so loads stay in flight across iterations — removes
//                the per-iteration vmcnt(0) barrier drain that serialized v1.

#define DDIM  2048
#define BSAMP 1024
#define KCOMP 10
#define MPAD  160                    // max n_k pad; Binom(1024,0.1)+6sigma
#define NT    64                     // block N tile
#define BK    32                     // d-elems per pipeline step
#define NITER (DDIM / BK)            // 64

typedef __attribute__((ext_vector_type(8))) short bf16x8;  // 8 bf16 = 4 VGPRs
typedef __attribute__((ext_vector_type(4))) float f32x4;

__device__ __forceinline__ short bfs(float x) {
    __hip_bfloat16 h = __float2bfloat16(x);   // RNE
    return *reinterpret_cast<short*>(&h);
}

// Kernel 1: counting-bucket the 1024 samples by component.
__global__ void build_map(const int* __restrict__ comp,
                          int* __restrict__ rowmap,
                          int* __restrict__ counts) {
    __shared__ int sc[KCOMP];
    const int t = threadIdx.x;
    if (t < KCOMP) sc[t] = 0;
    __syncthreads();
    const int c = comp[t];
    const int r = atomicAdd(&sc[c], 1);
    if (r < MPAD) rowmap[c * MPAD + r] = t;
    __syncthreads();
    if (t < KCOMP) counts[t] = sc[t];
}

// Kernel 2: zb[k*MPAD + slot][d] = bf16(z[rowmap[k][slot]][d]).
// Grid = KCOMP*MPAD blocks x 256 threads; each block converts one row.
// Pad slots read garbage rowmap -> masked in-bounds; values are finite and the
// epilogue masks slot >= count, so they are numerically irrelevant.
__global__ void zgather(const float* __restrict__ z,
                        const int* __restrict__ rowmap,
                        short* __restrict__ zb) {
    const int ks  = blockIdx.x;                 // k*MPAD + slot
    const int t   = threadIdx.x;                // 0..255, 8 elems each
    const int src = rowmap[ks] & (BSAMP - 1);
    const float* zr = z + (size_t)src * DDIM + t * 8;
    f32x4 x = *(const f32x4*)zr;
    f32x4 y = *(const f32x4*)(zr + 4);
    bf16x8 r;
#pragma unroll
    for (int i = 0; i < 4; ++i) { r[i] = bfs(x[i]); r[4 + i] = bfs(y[i]); }
    *(bf16x8*)(zb + (size_t)ks * DDIM + t * 8) = r;
}

// Kernel 3: grid = (2048/NT, KCOMP), block = 256 (4 waves).
// Block tile 160x64; wave tile 80x32 (mh = M-half, nh = N-half).
// A frag: lane holds zb row (mh*80+mt*16+fr), k-elems ko..ko+7  (16B load).
// B frag: lane holds L   row (n0+nh*32+nt*16+fr), same k-elems  (2x f32x4).
// C/D:    col = lane&15, row = (lane>>4)*4 + r   (m89-verified, unchanged).
__global__ __launch_bounds__(256, 3)
void gmm_gemm(const short* __restrict__ zb,
              const float* __restrict__ mvec,
              const float* __restrict__ Lmat,
              const int* __restrict__ rowmap,
              const int* __restrict__ counts,
              float* __restrict__ out) {
    const int t    = threadIdx.x;
    const int lane = t & 63;
    const int w    = t >> 6;
    const int mh   = w >> 1;
    const int nh   = w & 1;
    const int k    = blockIdx.y;
    const int n0   = blockIdx.x * NT;
    const int fr   = lane & 15;
    const int ko   = (lane >> 4) * 8;
    const float* Lk = Lmat + (size_t)k * DDIM * DDIM;
    const short* zk = zb + (size_t)k * MPAD * DDIM;

    const short* ap[5];
    const float* bp[2];
#pragma unroll
    for (int mt = 0; mt < 5; ++mt)
        ap[mt] = zk + (size_t)(mh * 80 + mt * 16 + fr) * DDIM + ko;
#pragma unroll
    for (int nt = 0; nt < 2; ++nt)
        bp[nt] = Lk + (size_t)(n0 + nh * 32 + nt * 16 + fr) * DDIM + ko;

    f32x4 acc[5][2];
#pragma unroll
    for (int mt = 0; mt < 5; ++mt) {
        acc[mt][0] = (f32x4){0.f, 0.f, 0.f, 0.f};
        acc[mt][1] = (f32x4){0.f, 0.f, 0.f, 0.f};
    }

    bf16x8 a0[5], a1[5];       // even / odd iteration A frags (static indexed)
    f32x4  b0[4], b1[4];       // even / odd iteration B fp32 (2 frags x 2)

    auto LOADA = [&](int it, bf16x8 (&a)[5]) {
#pragma unroll
        for (int mt = 0; mt < 5; ++mt)
            a[mt] = *(const bf16x8*)(ap[mt] + it * BK);
    };
    auto LOADB = [&](int it, f32x4 (&b)[4]) {
#pragma unroll
        for (int nt = 0; nt < 2; ++nt) {
            const float* p = bp[nt] + it * BK;
            b[2 * nt]     = *(const f32x4*)p;
            b[2 * nt + 1] = *(const f32x4*)(p + 4);
        }
    };
    auto COMPUTE = [&](bf16x8 (&a)[5], f32x4 (&b)[4]) {
        bf16x8 bb[2];
#pragma unroll
        for (int nt = 0; nt < 2; ++nt)
#pragma unroll
            for (int i = 0; i < 4; ++i) {
                bb[nt][i]     = bfs(b[2 * nt][i]);
                bb[nt][4 + i] = bfs(b[2 * nt + 1][i]);
            }
#pragma unroll
        for (int mt = 0; mt < 5; ++mt) {
            acc[mt][0] = __builtin_amdgcn_mfma_f32_16x16x32_bf16(a[mt], bb[0], acc[mt][0], 0, 0, 0);
            acc[mt][1] = __builtin_amdgcn_mfma_f32_16x16x32_bf16(a[mt], bb[1], acc[mt][1], 0, 0, 0);
        }
    };

    LOADA(0, a0); LOADB(0, b0);
    LOADA(1, a1); LOADB(1, b1);

    for (int it = 0; it < NITER - 2; it += 2) {
        COMPUTE(a0, b0);
        LOADA(it + 2, a0); LOADB(it + 2, b0);   // regs dead after COMPUTE; SSA
        COMPUTE(a1, b1);                        // renaming -> no copies, loads
        LOADA(it + 3, a1); LOADB(it + 3, b1);   // in flight across iterations
    }
    COMPUTE(a0, b0);
    COMPUTE(a1, b1);

    // epilogue: C/D layout col=lane&15, row=(lane>>4)*4+reg (m89-verified)
    const int cnt   = counts[k];
    const int rquad = (lane >> 4) * 4;
#pragma unroll
    for (int nt = 0; nt < 2; ++nt) {
        const int e = n0 + nh * 32 + nt * 16 + fr;
        const float mu = mvec[k * DDIM + e];
#pragma unroll
        for (int mt = 0; mt < 5; ++mt) {
            const int sb = mh * 80 + mt * 16 + rquad;
#pragma unroll
            for (int r = 0; r < 4; ++r) {
                const int slot = sb + r;
                if (slot < cnt) {
                    const int b = rowmap[k * MPAD + slot];
                    out[(size_t)b * DDIM + e] = acc[mt][nt][r] + mu;
                }
            }
        }
    }
}

extern "C" void kernel_launch(void* const* d_in, const int* in_sizes, int n_in,
                              void* d_out, int out_size, void* d_ws, size_t ws_size,
                              hipStream_t stream) {
    const float* z    = (const float*)d_in[0];
    const float* mvec = (const float*)d_in[1];
    const float* Lmat = (const float*)d_in[2];
    const int* comp   = (const int*)d_in[3];
    float* out        = (float*)d_out;

    int* rowmap = (int*)d_ws;                         // K*MPAD ints = 6400 B
    int* counts = rowmap + KCOMP * MPAD;              // K ints
    short* zb   = (short*)((char*)d_ws + 8192);       // 16B-aligned, 6.55 MB

    build_map<<<1, BSAMP, 0, stream>>>(comp, rowmap, counts);
    zgather<<<KCOMP * MPAD, 256, 0, stream>>>(z, rowmap, zb);
    gmm_gemm<<<dim3(DDIM / NT, KCOMP), 256, 0, stream>>>(zb, mvec, Lmat, rowmap,
                                                         counts, out);
}

// Round 2
// 279.465 us; speedup vs baseline: 1.2221x; 1.2221x over previous
//
#include <hip/hip_runtime.h>
#include <hip/hip_bf16.h>

// out[b,e] = m[c,e] + sum_d z[b,d] * L[c,e,d],  c = components[b]
// v3: K1 build_map (bucket), K2 zgather (gather+convert z -> bf16 zb),
// K3 gmm_gemm split-K over d (grid.z=4): LDS-staged coalesced loads
//     (global_load_lds 16B), A bf16 + B fp32 double-buffered (36 KB ->
//     4 blocks/CU so barrier drains overlap across blocks), swizzled LDS,
//     fp32 partials. K4 reduce_add: sum partials + mu, scatter to out.

#define DDIM  2048
#define BSAMP 1024
#define KCOMP 10
#define MPAD  160                      // max n_k pad; Binom(1024,0.1)+6sigma
#define NT    64                       // block N tile
#define BK    32                       // d-elems per iteration
#define SPLITS 4
#define ABYTES (MPAD * BK * 2)         // 10240  (bf16 A stage)
#define BBYTES (NT * BK * 4)           // 8192   (fp32 B stage)
#define STAGE_BYTES (ABYTES + BBYTES)  // 18432

typedef __attribute__((ext_vector_type(8))) short bf16x8;  // 8 bf16 = 4 VGPRs
typedef __attribute__((ext_vector_type(4))) float f32x4;

__device__ __forceinline__ void async16(void* lds, const void* g) {
    __builtin_amdgcn_global_load_lds(
        (const __attribute__((address_space(1))) void*)g,
        (__attribute__((address_space(3))) void*)lds, 16, 0, 0);
}

__device__ __forceinline__ short bfs(float x) {
    __hip_bfloat16 h = __float2bfloat16(x);   // RNE
    return *reinterpret_cast<short*>(&h);
}

// Kernel 1: counting-bucket the 1024 samples by component.
__global__ void build_map(const int* __restrict__ comp,
                          int* __restrict__ rowmap,
                          int* __restrict__ counts) {
    __shared__ int sc[KCOMP];
    const int t = threadIdx.x;
    if (t < KCOMP) sc[t] = 0;
    __syncthreads();
    const int c = comp[t];
    const int r = atomicAdd(&sc[c], 1);
    if (r < MPAD) rowmap[c * MPAD + r] = t;
    __syncthreads();
    if (t < KCOMP) counts[t] = sc[t];
}

// Kernel 2: zb[k*MPAD + slot][d] = bf16(z[rowmap[k][slot]][d]).
// Pad slots read garbage rowmap (masked in-bounds, finite) - epilogue masks.
__global__ void zgather(const float* __restrict__ z,
                        const int* __restrict__ rowmap,
                        short* __restrict__ zb) {
    const int ks  = blockIdx.x;                 // k*MPAD + slot
    const int t   = threadIdx.x;                // 0..255, 8 elems each
    const int src = rowmap[ks] & (BSAMP - 1);
    const float* zr = z + (size_t)src * DDIM + t * 8;
    f32x4 x = *(const f32x4*)zr;
    f32x4 y = *(const f32x4*)(zr + 4);
    bf16x8 r;
#pragma unroll
    for (int i = 0; i < 4; ++i) { r[i] = bfs(x[i]); r[4 + i] = bfs(y[i]); }
    *(bf16x8*)(zb + (size_t)ks * DDIM + t * 8) = r;
}

// Kernel 3: grid = (2048/NT, KCOMP, splits), block = 256 (4 waves).
// Block tile 160x64 over d-chunk of niter*BK; wave tile 80x32.
// LDS A region: 160 rows x 32 bf16 (64B row = 4 chunks); chunk for source
//   col-group g at row r stored at h = (g + (r>>1)) & 3  -> conflict-minimal.
// LDS B region: 64 rows x 32 fp32 (128B row = 8 chunks); stored at
//   h = g ^ (r&7) (XOR involution) -> conflict-minimal.
// Staging writes LDS linearly (global_load_lds: wave-uniform base + lane*16);
// the swizzle is applied by pre-swizzling the per-lane GLOBAL source column.
__global__ __launch_bounds__(256, 4)
void gmm_gemm(const short* __restrict__ zb,
              const float* __restrict__ mvec,
              const float* __restrict__ Lmat,
              const int* __restrict__ rowmap,
              const int* __restrict__ counts,
              float* __restrict__ out,
              float* __restrict__ partials,
              int niter, int write_partials) {
    __shared__ __attribute__((aligned(16))) char smem[2 * STAGE_BYTES];
    const int t    = threadIdx.x;
    const int lane = t & 63;
    const int w    = t >> 6;
    const int mh   = w >> 1;          // wave M-half (80 rows)
    const int nh   = w & 1;           // wave N-half (32 cols)
    const int k    = blockIdx.y;
    const int n0   = blockIdx.x * NT;
    const int d_base = blockIdx.z * niter * BK;
    const float* Lk = Lmat + (size_t)k * DDIM * DDIM;
    const short* zk = zb + (size_t)k * MPAD * DDIM;

    // A staging: 640 chunks (row = c>>2, h = c&3), instrs j=0,1 all threads,
    // j=2 for t<128 (waves 0,1 -> wave-uniform predicate).
    int arow[3], acol[3];
#pragma unroll
    for (int j = 0; j < 3; ++j) {
        const int c = j * 256 + t;
        const int r = c >> 2;
        arow[j] = r;
        acol[j] = (((c & 3) - (r >> 1)) & 3) * 8;   // source bf16 col (pre-swz)
    }
    // B staging: 512 chunks (row = c>>3, h = c&7), instrs j=0,1.
    int brow[2], bcol[2];
#pragma unroll
    for (int j = 0; j < 2; ++j) {
        const int c = j * 256 + t;
        const int r = c >> 3;
        brow[j] = r;
        bcol[j] = ((t & 7) ^ (r & 7)) * 4;          // source fp32 col (pre-swz)
    }
    const unsigned ub = (unsigned)(t & ~63) * 16;   // wave-uniform byte base

    auto stage = [&](int buf, int it) {
        char* lb = smem + buf * STAGE_BYTES;
        const int d0 = d_base + it * BK;
        async16(lb + ub,        zk + (size_t)arow[0] * DDIM + d0 + acol[0]);
        async16(lb + 4096 + ub, zk + (size_t)arow[1] * DDIM + d0 + acol[1]);
        if (t < 128)
            async16(lb + 8192 + ub, zk + (size_t)arow[2] * DDIM + d0 + acol[2]);
        async16(lb + ABYTES + ub,
                Lk + (size_t)(n0 + brow[0]) * DDIM + d0 + bcol[0]);
        async16(lb + ABYTES + 4096 + ub,
                Lk + (size_t)(n0 + brow[1]) * DDIM + d0 + bcol[1]);
    };

    f32x4 acc[5][2];
#pragma unroll
    for (int mt = 0; mt < 5; ++mt) {
        acc[mt][0] = (f32x4){0.f, 0.f, 0.f, 0.f};
        acc[mt][1] = (f32x4){0.f, 0.f, 0.f, 0.f};
    }

    stage(0, 0);
    __syncthreads();                 // drains vmcnt -> buf0 ready

    const int fr = lane & 15;        // frag row
    const int g  = lane >> 4;        // k-group (8 elems) of this lane

    for (int it = 0; it < niter; ++it) {
        if (it + 1 < niter) stage((it + 1) & 1, it + 1);
        const char* lb = smem + (it & 1) * STAGE_BYTES;
        const short* A = (const short*)lb;
        const float* B = (const float*)(lb + ABYTES);

        bf16x8 bb[2];
#pragma unroll
        for (int nt = 0; nt < 2; ++nt) {
            const int rb = nh * 32 + nt * 16 + fr;
            const int h0 = ((2 * g)     ^ (rb & 7)) * 4;
            const int h1 = ((2 * g + 1) ^ (rb & 7)) * 4;
            f32x4 x = *(const f32x4*)(B + rb * 32 + h0);
            f32x4 y = *(const f32x4*)(B + rb * 32 + h1);
#pragma unroll
            for (int i = 0; i < 4; ++i) {
                bb[nt][i]     = bfs(x[i]);
                bb[nt][4 + i] = bfs(y[i]);
            }
        }
#pragma unroll
        for (int mt = 0; mt < 5; ++mt) {
            const int ra = mh * 80 + mt * 16 + fr;
            const int gs = ((g + (ra >> 1)) & 3) * 8;
            bf16x8 a = *(const bf16x8*)(A + ra * 32 + gs);
            acc[mt][0] = __builtin_amdgcn_mfma_f32_16x16x32_bf16(a, bb[0], acc[mt][0], 0, 0, 0);
            acc[mt][1] = __builtin_amdgcn_mfma_f32_16x16x32_bf16(a, bb[1], acc[mt][1], 0, 0, 0);
        }
        __syncthreads();             // cur buf consumed; prefetch drained
    }

    // epilogue: C/D layout col=lane&15, row=(lane>>4)*4+reg (m89-verified)
    const int rquad = (lane >> 4) * 4;
    if (write_partials) {
        float* P = partials +
                   ((size_t)blockIdx.z * KCOMP + k) * MPAD * DDIM;
#pragma unroll
        for (int nt = 0; nt < 2; ++nt) {
            const int e = n0 + nh * 32 + nt * 16 + fr;
#pragma unroll
            for (int mt = 0; mt < 5; ++mt) {
                const int sb = mh * 80 + mt * 16 + rquad;
#pragma unroll
                for (int r = 0; r < 4; ++r)
                    P[(size_t)(sb + r) * DDIM + e] = acc[mt][nt][r];
            }
        }
    } else {
        const int cnt = counts[k];
#pragma unroll
        for (int nt = 0; nt < 2; ++nt) {
            const int e = n0 + nh * 32 + nt * 16 + fr;
            const float mu = mvec[k * DDIM + e];
#pragma unroll
            for (int mt = 0; mt < 5; ++mt) {
                const int sb = mh * 80 + mt * 16 + rquad;
#pragma unroll
                for (int r = 0; r < 4; ++r) {
                    const int slot = sb + r;
                    if (slot < cnt) {
                        const int b = rowmap[k * MPAD + slot];
                        out[(size_t)b * DDIM + e] = acc[mt][nt][r] + mu;
                    }
                }
            }
        }
    }
}

// Kernel 4: out[b,e] = mu[k,e] + sum_s partials[s][k][slot][e]
__global__ void reduce_add(const float* __restrict__ partials,
                           const float* __restrict__ mvec,
                           const int* __restrict__ rowmap,
                           const int* __restrict__ counts,
                           float* __restrict__ out) {
    const int ks   = blockIdx.x;               // k*MPAD + slot
    const int k    = ks / MPAD;
    const int slot = ks - k * MPAD;
    if (slot >= counts[k]) return;
    const int b = rowmap[ks];
    const int e = threadIdx.x * 8;
    f32x4 s0 = (f32x4){0.f, 0.f, 0.f, 0.f};
    f32x4 s1 = (f32x4){0.f, 0.f, 0.f, 0.f};
#pragma unroll
    for (int s = 0; s < SPLITS; ++s) {
        const float* p = partials + ((size_t)s * KCOMP * MPAD + ks) * DDIM + e;
        s0 += *(const f32x4*)p;
        s1 += *(const f32x4*)(p + 4);
    }
    const float* mu = mvec + k * DDIM + e;
    f32x4 m0 = *(const f32x4*)mu;
    f32x4 m1 = *(const f32x4*)(mu + 4);
    float* o = out + (size_t)b * DDIM + e;
    *(f32x4*)o       = s0 + m0;
    *(f32x4*)(o + 4) = s1 + m1;
}

extern "C" void kernel_launch(void* const* d_in, const int* in_sizes, int n_in,
                              void* d_out, int out_size, void* d_ws, size_t ws_size,
                              hipStream_t stream) {
    const float* z    = (const float*)d_in[0];
    const float* mvec = (const float*)d_in[1];
    const float* Lmat = (const float*)d_in[2];
    const int* comp   = (const int*)d_in[3];
    float* out        = (float*)d_out;

    int* rowmap = (int*)d_ws;                         // K*MPAD ints = 6400 B
    int* counts = rowmap + KCOMP * MPAD;              // K ints
    const size_t zb_bytes = (size_t)KCOMP * MPAD * DDIM * 2;      // 6.55 MB
    const size_t pt_bytes = (size_t)SPLITS * KCOMP * MPAD * DDIM * 4; // 52.4 MB
    short* zb       = (short*)((char*)d_ws + 8192);
    float* partials = (float*)((char*)d_ws + 8192 + zb_bytes);

    const int splits = (ws_size >= 8192 + zb_bytes + pt_bytes) ? SPLITS : 1;

    build_map<<<1, BSAMP, 0, stream>>>(comp, rowmap, counts);
    zgather<<<KCOMP * MPAD, 256, 0, stream>>>(z, rowmap, zb);
    gmm_gemm<<<dim3(DDIM / NT, KCOMP, splits), 256, 0, stream>>>(
        zb, mvec, Lmat, rowmap, counts, out, partials,
        DDIM / (BK * splits), splits > 1 ? 1 : 0);
    if (splits > 1)
        reduce_add<<<KCOMP * MPAD, 256, 0, stream>>>(partials, mvec, rowmap,
                                                     counts, out);
}